// Round 1
// 289.055 us; speedup vs baseline: 1.0816x; 1.0816x over previous
//
#include <hip/hip_runtime.h>
#include <stdint.h>

// BitLinear: y = (int8(x) @ unpack2bit(Wp)^T) * amax/(127*ws) + bias
// M=16384 tokens, K=2048, N=2048. Integer GEMM via mfma_i32_16x16x64_i8.
// R3: GEMM rebuilt as 256x256-tile, 8-wave, BK=128B, 4-phase-per-K-tile
//     software pipeline with COUNTED vmcnt (never 0 in main loop), raw
//     s_barrier, setprio around MFMA clusters, XOR-swizzled LDS (slot =
//     chunk ^ (row&7), realized via pre-swizzled global source since
//     global_load_lds writes lane-linear), XCD-aware block swizzle.
//     Stage order per K-tile = first-need order: A-mh0, B-nh0, B-nh1, A-mh1
//     (B staged in 32-row stripes so halves align with nh quadrants).
//     Waits per phase: 4/4/6/4; prologue 4; epilogue drains 2->0.

typedef __attribute__((ext_vector_type(4))) int int4v;

#define GLOBAL_AS __attribute__((address_space(1)))
#define LDS_AS    __attribute__((address_space(3)))

static constexpr int MK = 2048;   // K (inner dim)
static constexpr int NN = 2048;   // out features
static constexpr int MM = 16384;  // tokens

// ---------------- activation quant: one block per token row (unchanged) ----
__global__ void quant_kernel(const float* __restrict__ x,
                             const float* __restrict__ wscale,
                             signed char* __restrict__ xq,
                             float* __restrict__ rf) {
    const int m = blockIdx.x;
    const int t = threadIdx.x;
    const float4* xr = (const float4*)(x + (size_t)m * MK);  // 512 float4/row
    float4 v0 = xr[t];
    float4 v1 = xr[t + 256];
    float amax = fmaxf(fmaxf(fabsf(v0.x), fabsf(v0.y)),
                       fmaxf(fabsf(v0.z), fabsf(v0.w)));
    amax = fmaxf(amax, fmaxf(fmaxf(fabsf(v1.x), fabsf(v1.y)),
                             fmaxf(fabsf(v1.z), fabsf(v1.w))));
    #pragma unroll
    for (int off = 32; off >= 1; off >>= 1)
        amax = fmaxf(amax, __shfl_xor(amax, off));
    __shared__ float smax[4];
    if ((t & 63) == 0) smax[t >> 6] = amax;
    __syncthreads();
    float a0 = fmaxf(fmaxf(smax[0], smax[1]), fmaxf(smax[2], smax[3]));
    a0 = fmaxf(a0, 1e-5f);
    const float scale = 127.0f / a0;
    if (t == 0) rf[m] = a0 / (127.0f * wscale[0]);

    auto q = [&](float f) -> int {
        float r = rintf(f * scale);        // round-half-to-even
        r = fminf(fmaxf(r, -128.0f), 127.0f);
        return (int)r;
    };
    int p0 = (q(v0.x) & 255) | ((q(v0.y) & 255) << 8) |
             ((q(v0.z) & 255) << 16) | ((q(v0.w) & 255) << 24);
    int p1 = (q(v1.x) & 255) | ((q(v1.y) & 255) << 8) |
             ((q(v1.z) & 255) << 16) | ((q(v1.w) & 255) << 24);
    int* xqr = (int*)(xq + (size_t)m * MK);
    xqr[t]       = p0;
    xqr[t + 256] = p1;
}

// ---------------- weight unpack (unchanged) --------------------------------
__global__ void unpack_kernel(const int* __restrict__ packed,
                              signed char* __restrict__ W) {
    const int idx = blockIdx.x * 256 + threadIdx.x;   // 0 .. 512*512
    const int r  = idx >> 9;        // packed row
    const int kq = idx & 511;       // k/4
    const int4 p = ((const int4*)packed)[idx];        // 4 consecutive k
    int* Wi = (int*)W;              // 512 ints per W row
    #pragma unroll
    for (int i = 0; i < 4; i++) {
        const int sh = 2 * i;
        int b0 = ((((p.x >> sh) & 3) - 1) & 255);
        int b1 = ((((p.y >> sh) & 3) - 1) & 255);
        int b2 = ((((p.z >> sh) & 3) - 1) & 255);
        int b3 = ((((p.w >> sh) & 3) - 1) & 255);
        Wi[(i * 512 + r) * 512 + kq] = b0 | (b1 << 8) | (b2 << 16) | (b3 << 24);
    }
}

// ---------------- int8 GEMM: 256x256 tile, 4-phase pipelined ---------------
// LDS (128 KiB): buf{0,1} x [A: 32KiB | B: 32KiB]. Within a plane, stage-half
// h (16 KiB) holds its 128 rows linearly (128 B/row); logical 16B chunk c of
// a row with in-half index rw sits at slot c ^ (rw&7).  A halves stripe at 64
// rows (mh quadrants), B halves at 32 rows (nh quadrants).
#define WAITV(N) asm volatile("s_waitcnt vmcnt(" #N ")" ::: "memory")

__device__ __forceinline__ void stage_half(const signed char* __restrict__ src,
                                           int row0, int k0, int h, int ss,
                                           unsigned char* plane,
                                           int wave, int lane) {
    // lane writes LDS at (wave*2+j)*1024 + lane*16 -> in-half row rw, slot lane&7.
    // Fetch the logical chunk that belongs in that slot: c = (lane&7)^(rw&7),
    // and rw&7 == lane>>3 for all groups.
    const int csrc = (((lane & 7) ^ (lane >> 3)) << 4);
    #pragma unroll
    for (int j = 0; j < 2; ++j) {
        const int rw = wave * 16 + j * 8 + (lane >> 3);          // 0..127
        const int r  = (rw & ((1 << ss) - 1)) + (h << ss)
                     + ((rw >> ss) << (ss + 1));                 // tile row
        const signed char* ga = src + (size_t)(row0 + r) * MK + k0 + csrc;
        __builtin_amdgcn_global_load_lds((const GLOBAL_AS void*)ga,
            (LDS_AS void*)(plane + (h << 14) + (wave * 2 + j) * 1024),
            16, 0, 0);
    }
}

// One phase: ds-load fragments, issue one half-tile prefetch, counted wait,
// raw barrier, 16 MFMAs (one C-quadrant x BK=128) under setprio.
#define PH(MH, NH, DO_READA, STAGE, WAIT)                                      \
  do {                                                                         \
    if (DO_READA) {                                                            \
      _Pragma("unroll")                                                        \
      for (int mt = 0; mt < 4; ++mt) {                                         \
        a[mt][0] = *(const int4v*)(shp + cb + aoff0 + (MH)*16384 + mt*2048);   \
        a[mt][1] = *(const int4v*)(shp + cb + aoff1 + (MH)*16384 + mt*2048);   \
      }                                                                        \
    }                                                                          \
    _Pragma("unroll")                                                          \
    for (int nf = 0; nf < 2; ++nf) {                                           \
      b[nf][0] = *(const int4v*)(shp + cb + boff0 + (NH)*16384 + nf*2048);     \
      b[nf][1] = *(const int4v*)(shp + cb + boff1 + (NH)*16384 + nf*2048);     \
    }                                                                          \
    STAGE;                                                                     \
    WAIT;                                                                      \
    __builtin_amdgcn_s_barrier();                                              \
    __builtin_amdgcn_sched_barrier(0);                                         \
    __builtin_amdgcn_s_setprio(1);                                             \
    _Pragma("unroll")                                                          \
    for (int mt = 0; mt < 4; ++mt) {                                           \
      _Pragma("unroll")                                                        \
      for (int nf = 0; nf < 2; ++nf) {                                         \
        acc[(MH)*4+mt][(NH)*2+nf] = __builtin_amdgcn_mfma_i32_16x16x64_i8(     \
            a[mt][0], b[nf][0], acc[(MH)*4+mt][(NH)*2+nf], 0, 0, 0);           \
        acc[(MH)*4+mt][(NH)*2+nf] = __builtin_amdgcn_mfma_i32_16x16x64_i8(     \
            a[mt][1], b[nf][1], acc[(MH)*4+mt][(NH)*2+nf], 0, 0, 0);           \
      }                                                                        \
    }                                                                          \
    __builtin_amdgcn_s_setprio(0);                                             \
  } while (0)

__global__ void __launch_bounds__(512, 2)
gemm_kernel(const signed char* __restrict__ xq,   // [M][K]
            const signed char* __restrict__ W,    // [N][K]
            const float* __restrict__ rf,         // [M]
            const float* __restrict__ bias,       // [N]
            float* __restrict__ out) {            // [M][N]
    __shared__ __attribute__((aligned(16))) unsigned char sh[131072];
    unsigned char* shp = sh;

    const int tid  = threadIdx.x;
    const int wave = tid >> 6;
    const int lane = tid & 63;
    const int wm = wave >> 2;          // 0..1: wave's 128-row M band
    const int wn = wave & 3;           // 0..3: wave's 64-col N band

    // XCD-aware swizzle: 512 blocks = 8 XCDs x 64 contiguous chunks
    const int bs = ((blockIdx.x & 7) << 6) | (blockIdx.x >> 3);
    const int m0 = (bs >> 3) << 8;     // 64 M-tiles
    const int n0 = (bs & 7) << 8;      // 8  N-tiles

    // fragment addressing: lane holds row fr, k-chunk ks*4+lq of each frag
    const int fr = lane & 15, lq = lane >> 4, f7 = fr & 7;
    const int cks0  = (lq ^ f7) << 4;                 // ks=0 slot byte
    const int aoff0 = (wm * 64 + fr) * 128 + cks0;    // + MH*16384 + mt*2048
    const int aoff1 = aoff0 ^ 64;                     // ks=1 (chunk c^4)
    const int boff0 = 32768 + (wn * 32 + fr) * 128 + cks0;  // + NH*16384 + nf*2048
    const int boff1 = boff0 ^ 64;

    int4v a[4][2], b[2][2];
    int4v acc[8][4] = {};

    // prologue: stage tile 0 into buf0 in first-need order; keep B1,A1 in flight
    stage_half(xq, m0, 0, 0, 6, shp,        wave, lane);   // A mh0
    stage_half(W,  n0, 0, 0, 5, shp + 32768, wave, lane);  // B nh0
    stage_half(W,  n0, 0, 1, 5, shp + 32768, wave, lane);  // B nh1
    stage_half(xq, m0, 0, 1, 6, shp,        wave, lane);   // A mh1
    WAITV(4);
    __builtin_amdgcn_s_barrier();
    __builtin_amdgcn_sched_barrier(0);

    #pragma unroll 1
    for (int t = 0; t < 15; ++t) {
        const int cb = (t & 1) << 16;       // current buffer
        const int nb = cb ^ 65536;          // next buffer
        const int k1 = (t + 1) << 7;
        PH(0, 0, 1, stage_half(xq, m0, k1, 0, 6, shp + nb,        wave, lane), WAITV(4));
        PH(0, 1, 0, stage_half(W,  n0, k1, 0, 5, shp + nb + 32768, wave, lane), WAITV(4));
        PH(1, 0, 1, stage_half(W,  n0, k1, 1, 5, shp + nb + 32768, wave, lane), WAITV(6));
        PH(1, 1, 0, stage_half(xq, m0, k1, 1, 6, shp + nb,        wave, lane), WAITV(4));
    }
    {   // tail tile 15 (buf1): no prefetch, drain 2 -> 0
        const int cb = 65536;
        PH(0, 0, 1, (void)0, WAITV(2));
        PH(0, 1, 0, (void)0, WAITV(0));
        PH(1, 0, 1, (void)0, (void)0);
        PH(1, 1, 0, (void)0, (void)0);
    }

    // epilogue: C/D map col=lane&15, row=(lane>>4)*4+reg
    const int col = lane & 15;
    const int rq  = (lane >> 4) * 4;
    const int nbase = n0 + wn * 64 + col;
    float bv[4];
    #pragma unroll
    for (int nf = 0; nf < 4; ++nf) bv[nf] = bias[nbase + nf * 16];
    #pragma unroll
    for (int mf = 0; mf < 8; ++mf) {
        #pragma unroll
        for (int rr = 0; rr < 4; ++rr) {
            const int m = m0 + wm * 128 + mf * 16 + rq + rr;
            const float frm = rf[m];
            float* orow = out + (size_t)m * NN;
            #pragma unroll
            for (int nf = 0; nf < 4; ++nf)
                orow[nbase + nf * 16] = (float)acc[mf][nf][rr] * frm + bv[nf];
        }
    }
}

extern "C" void kernel_launch(void* const* d_in, const int* in_sizes, int n_in,
                              void* d_out, int out_size, void* d_ws, size_t ws_size,
                              hipStream_t stream) {
    const float* x      = (const float*)d_in[0];
    const int*   packed = (const int*)d_in[1];
    const float* wscale = (const float*)d_in[2];
    const float* bias   = (const float*)d_in[3];
    float* out = (float*)d_out;

    // workspace: xq [16384*2048] i8 | W [2048*2048] i8 | rf [16384] f32
    signed char* xq = (signed char*)d_ws;
    signed char* W  = xq + (size_t)MM * MK;
    float*       rf = (float*)(W + (size_t)NN * MK);

    quant_kernel<<<MM, 256, 0, stream>>>(x, wscale, xq, rf);
    unpack_kernel<<<(512 * 512) / 256, 256, 0, stream>>>(packed, W);
    gemm_kernel<<<dim3(512), 512, 0, stream>>>(xq, W, rf, bias, out);
}